// Round 2
// baseline (619.910 us; speedup 1.0000x reference)
//
#include <hip/hip_runtime.h>
#include <hip/hip_bf16.h>

typedef unsigned short u16;
typedef __attribute__((ext_vector_type(8))) short short8;  // 8 bf16 (4 VGPRs)
typedef __attribute__((ext_vector_type(4))) float f32x4;

#define BATCH 8
#define CH 256
#define NPIX 4096
#define KD 32   // C/8

static __device__ __forceinline__ u16 f2bf(float f) {
  union { __hip_bfloat16 h; u16 u; } cv;
  cv.h = __float2bfloat16(f);
  return cv.u;
}

static __device__ __forceinline__ void gload_lds16(const void* g, void* l) {
  __builtin_amdgcn_global_load_lds(
      (const __attribute__((address_space(1))) void*)g,
      (__attribute__((address_space(3))) void*)l,
      16, 0, 0);
}

// ---------------------------------------------------------------------------
// Kernel 1: projections. x [B][C][N] f32 -> fT/gT [B][N][32] bf16, hh [B][C][N] bf16
// Block: 256 threads, handles one batch x 32-pixel tile. x tile in LDS,
// all per-(c,p) LDS reads are wave-uniform -> broadcast, no conflicts.
// ---------------------------------------------------------------------------
__global__ __launch_bounds__(256) void proj_kernel(
    const float* __restrict__ x,
    const float* __restrict__ Wf, const float* __restrict__ bfp,
    const float* __restrict__ Wg, const float* __restrict__ bgp,
    const float* __restrict__ Wh, const float* __restrict__ bhp,
    u16* __restrict__ fT, u16* __restrict__ gT, u16* __restrict__ hhb)
{
  __shared__ float xs[CH][36];  // 36: 16B-aligned rows (144 B), bank-shifted
  const int b  = blockIdx.x >> 7;          // 128 tiles per batch
  const int n0 = (blockIdx.x & 127) * 32;
  const int t  = threadIdx.x;

  const float* xb = x + ((size_t)b * CH) * NPIX + n0;
  #pragma unroll
  for (int kk = 0; kk < 8; ++kk) {
    int v = kk * 256 + t;        // float4 slot, 2048 total = 256 rows x 8
    int c = v >> 3, p4 = v & 7;
    float4 d = *(const float4*)(xb + (size_t)c * NPIX + p4 * 4);
    *(float4*)&xs[c][p4 * 4] = d;
  }
  __syncthreads();

  // hh: thread t owns output channel o = t, all 32 pixels
  const int o = t;
  float acch[32];
  #pragma unroll
  for (int p = 0; p < 32; ++p) acch[p] = bhp[o];

  // f/g: o2 = t&63 (0-31 -> f, 32-63 -> g), pixel group (t>>6)*8
  const int o2 = t & 63;
  const int oo = o2 & 31;
  const bool isf = o2 < 32;
  const float* Wfg = isf ? Wf : Wg;
  const float bias2 = isf ? bfp[oo] : bgp[oo];
  const int pg = (t >> 6) * 8;
  float accf[8];
  #pragma unroll
  for (int p = 0; p < 8; ++p) accf[p] = bias2;

  const float* whr  = Wh  + o * CH;
  const float* wfgr = Wfg + oo * CH;
  for (int c = 0; c < CH; ++c) {
    float wh = whr[c];
    float wf = wfgr[c];
    #pragma unroll
    for (int p4 = 0; p4 < 8; ++p4) {
      float4 xv = *(const float4*)&xs[c][p4 * 4];
      acch[p4*4+0] = fmaf(wh, xv.x, acch[p4*4+0]);
      acch[p4*4+1] = fmaf(wh, xv.y, acch[p4*4+1]);
      acch[p4*4+2] = fmaf(wh, xv.z, acch[p4*4+2]);
      acch[p4*4+3] = fmaf(wh, xv.w, acch[p4*4+3]);
    }
    #pragma unroll
    for (int p = 0; p < 8; ++p) accf[p] = fmaf(wf, xs[c][pg + p], accf[p]);
  }

  u16* hrow = hhb + ((size_t)b * CH + o) * NPIX + n0;
  #pragma unroll
  for (int q = 0; q < 4; ++q) {
    uint4 u;
    u.x = f2bf(acch[q*8+0]) | ((unsigned)f2bf(acch[q*8+1]) << 16);
    u.y = f2bf(acch[q*8+2]) | ((unsigned)f2bf(acch[q*8+3]) << 16);
    u.z = f2bf(acch[q*8+4]) | ((unsigned)f2bf(acch[q*8+5]) << 16);
    u.w = f2bf(acch[q*8+6]) | ((unsigned)f2bf(acch[q*8+7]) << 16);
    *(uint4*)(hrow + q * 8) = u;
  }
  u16* dst = (isf ? fT : gT) + ((size_t)b * NPIX + n0 + pg) * KD + oo;
  #pragma unroll
  for (int p = 0; p < 8; ++p) dst[(size_t)p * KD] = f2bf(accf[p]);
}

// ---------------------------------------------------------------------------
// Kernel 2: s = f^T g (one 16x16x32 MFMA per tile), softmax (no max-sub:
// |s| <= ~25, f32 exp is safe), write attn f32 to d_out (+ bf16 stash).
// Block: 256 thr = 4 waves; 16 rows; wave w covers j in [w*1024,(w+1)*1024).
// ---------------------------------------------------------------------------
template<bool STASH>
__global__ __launch_bounds__(256) void attn_kernel(
    const u16* __restrict__ fT, const u16* __restrict__ gT,
    float* __restrict__ attn_out, u16* __restrict__ attn_b16)
{
  const int b  = blockIdx.x >> 8;          // 256 row-tiles per batch
  const int i0 = (blockIdx.x & 255) * 16;
  const int t = threadIdx.x;
  const int w = t >> 6, l = t & 63;
  const int lg = l >> 4, lm = l & 15;

  const u16* fb = fT + ((size_t)b * NPIX + i0) * KD;
  const u16* gb = gT + (size_t)b * NPIX * KD;
  // A-frag: lane holds A[row=lm][k=lg*8..+8] = fT[i0+lm][...]
  short8 af = *(const short8*)(fb + lm * KD + lg * 8);
  f32x4 zero4 = {0.f, 0.f, 0.f, 0.f};

  float sum[4] = {0.f, 0.f, 0.f, 0.f};
  const int jbase = w * 1024;
  for (int jt = 0; jt < 64; ++jt) {
    int j0 = jbase + jt * 16;
    short8 bg8 = *(const short8*)(gb + (size_t)(j0 + lm) * KD + lg * 8);
    f32x4 s = __builtin_amdgcn_mfma_f32_16x16x32_bf16(af, bg8, zero4, 0, 0, 0);
    #pragma unroll
    for (int r = 0; r < 4; ++r) sum[r] += __expf(s[r]);
  }
  // reduce over the 16 lanes (lm) of each lane-group (rows live on lg,r)
  #pragma unroll
  for (int m = 1; m < 16; m <<= 1) {
    #pragma unroll
    for (int r = 0; r < 4; ++r) sum[r] += __shfl_xor(sum[r], m, 64);
  }
  __shared__ float part[4][16];
  __shared__ float invs[16];
  if (lm == 0) {
    #pragma unroll
    for (int r = 0; r < 4; ++r) part[w][lg * 4 + r] = sum[r];
  }
  __syncthreads();
  if (t < 16) invs[t] = 1.0f / (part[0][t] + part[1][t] + part[2][t] + part[3][t]);
  __syncthreads();
  float is4[4];
  #pragma unroll
  for (int r = 0; r < 4; ++r) is4[r] = invs[lg * 4 + r];

  float* arow = attn_out + ((size_t)b * NPIX + i0) * NPIX;
  u16*   brow = attn_b16 + ((size_t)b * NPIX + i0) * NPIX;
  for (int jt = 0; jt < 64; ++jt) {
    int j0 = jbase + jt * 16;
    short8 bg8 = *(const short8*)(gb + (size_t)(j0 + lm) * KD + lg * 8);
    f32x4 s = __builtin_amdgcn_mfma_f32_16x16x32_bf16(af, bg8, zero4, 0, 0, 0);
    #pragma unroll
    for (int r = 0; r < 4; ++r) {
      float v = __expf(s[r]) * is4[r];
      int i = lg * 4 + r;                  // D-layout: row=(lane>>4)*4+reg
      arow[(size_t)i * NPIX + j0 + lm] = v;
      if (STASH) brow[(size_t)i * NPIX + j0 + lm] = f2bf(v);
    }
  }
}

// ---------------------------------------------------------------------------
// Kernel 3: out[b][c][i] = gamma * sum_j hh[c][j]*attn[i][j] + x[b][c][i]
// GEMM: M=C=256 (full, attn read once), N_tile=64 (i), K=4096 (j), BK=32.
// A = hh [c][j] bf16 row-major, B^T = attn [i][j] -> both frags are 16B
// contiguous loads. m97 structure: global_load_lds staging, 4 waves,
// wave tile 64(m) x 64(n), 16 MFMA / K-step.
// ---------------------------------------------------------------------------
template<bool BF16B>
__global__ __launch_bounds__(256) void pv_kernel(
    const u16* __restrict__ hhb, const u16* __restrict__ attn_b16,
    const float* __restrict__ attn_f32, const float* __restrict__ x,
    const float* __restrict__ gamma, float* __restrict__ outp)
{
  __shared__ u16 Alds[CH * KD];   // 16 KB: [256 c][32 j]
  __shared__ u16 Blds[64 * KD];   // 4 KB:  [64 i][32 j]
  const int b  = blockIdx.x >> 6;          // 64 n-tiles per batch
  const int n0 = (blockIdx.x & 63) * 64;
  const int t = threadIdx.x;
  const int w = t >> 6, l = t & 63;
  const int lg = l >> 4, lm = l & 15;

  const u16* hb = hhb + (size_t)b * CH * NPIX;
  f32x4 zero4 = {0.f, 0.f, 0.f, 0.f};
  f32x4 acc[4][4];
  #pragma unroll
  for (int mf = 0; mf < 4; ++mf)
    #pragma unroll
    for (int nf = 0; nf < 4; ++nf) acc[mf][nf] = zero4;

  const int srow = l >> 2;   // 0..15 within a wave's staging stripe
  const int sslot = l & 3;

  for (int k0 = 0; k0 < NPIX; k0 += KD) {
    // stage A (16 KB): wave-linear LDS dest = base + lane*16
    #pragma unroll
    for (int q = 0; q < 4; ++q) {
      int row = (w * 4 + q) * 16 + srow;
      gload_lds16(hb + (size_t)row * NPIX + k0 + sslot * 8,
                  Alds + (size_t)(w * 4 + q) * 512 + l * 8);
    }
    // stage B (4 KB)
    if (BF16B) {
      int row = w * 16 + srow;
      gload_lds16(attn_b16 + ((size_t)b * NPIX + n0 + row) * NPIX + k0 + sslot * 8,
                  Blds + (size_t)w * 512 + l * 8);
    } else {
      int row = t >> 2, slot = t & 3;
      const float* src = attn_f32 + ((size_t)b * NPIX + n0 + row) * NPIX + k0 + slot * 8;
      float4 v0 = *(const float4*)src;
      float4 v1 = *(const float4*)(src + 4);
      uint4 u;
      u.x = f2bf(v0.x) | ((unsigned)f2bf(v0.y) << 16);
      u.y = f2bf(v0.z) | ((unsigned)f2bf(v0.w) << 16);
      u.z = f2bf(v1.x) | ((unsigned)f2bf(v1.y) << 16);
      u.w = f2bf(v1.z) | ((unsigned)f2bf(v1.w) << 16);
      *(uint4*)(Blds + row * KD + slot * 8) = u;
    }
    __syncthreads();   // drains vmcnt (global_load_lds) + lgkmcnt

    short8 afr[4], bfr[4];
    #pragma unroll
    for (int mf = 0; mf < 4; ++mf)
      afr[mf] = *(const short8*)(Alds + (w * 64 + mf * 16 + lm) * KD + lg * 8);
    #pragma unroll
    for (int nf = 0; nf < 4; ++nf)
      bfr[nf] = *(const short8*)(Blds + (nf * 16 + lm) * KD + lg * 8);
    #pragma unroll
    for (int mf = 0; mf < 4; ++mf)
      #pragma unroll
      for (int nf = 0; nf < 4; ++nf)
        acc[mf][nf] = __builtin_amdgcn_mfma_f32_16x16x32_bf16(afr[mf], bfr[nf],
                                                              acc[mf][nf], 0, 0, 0);
    __syncthreads();
  }

  const float gm = gamma[0];
  #pragma unroll
  for (int mf = 0; mf < 4; ++mf) {
    #pragma unroll
    for (int r = 0; r < 4; ++r) {
      int c = w * 64 + mf * 16 + lg * 4 + r;
      #pragma unroll
      for (int nf = 0; nf < 4; ++nf) {
        int i = n0 + nf * 16 + lm;
        size_t idx = ((size_t)b * CH + c) * NPIX + i;
        outp[idx] = fmaf(gm, acc[mf][nf][r], x[idx]);
      }
    }
  }
}

// ---------------------------------------------------------------------------
extern "C" void kernel_launch(void* const* d_in, const int* in_sizes, int n_in,
                              void* d_out, int out_size, void* d_ws, size_t ws_size,
                              hipStream_t stream) {
  const float* x     = (const float*)d_in[0];
  const float* Wf    = (const float*)d_in[1];
  const float* bf    = (const float*)d_in[2];
  const float* Wg    = (const float*)d_in[3];
  const float* bg    = (const float*)d_in[4];
  const float* Wh    = (const float*)d_in[5];
  const float* bh    = (const float*)d_in[6];
  const float* gamma = (const float*)d_in[7];

  float* outp = (float*)d_out;
  float* attn_out = outp + (size_t)BATCH * CH * NPIX;   // out | attention

  // ws layout: fT (2MB) | gT (2MB) | hh (16MB) | attn bf16 stash (256MB, optional)
  u16* fT = (u16*)d_ws;
  u16* gT = fT + (size_t)BATCH * NPIX * KD;
  u16* hh = gT + (size_t)BATCH * NPIX * KD;
  u16* ast = hh + (size_t)BATCH * CH * NPIX;
  const size_t need_full = (size_t)2 * BATCH * NPIX * KD * 2
                         + (size_t)BATCH * CH * NPIX * 2
                         + (size_t)BATCH * NPIX * NPIX * 2;   // 289,406,976 B
  const bool stash = ws_size >= need_full;

  proj_kernel<<<dim3(BATCH * (NPIX / 32)), dim3(256), 0, stream>>>(
      x, Wf, bf, Wg, bg, Wh, bh, fT, gT, hh);

  if (stash) {
    attn_kernel<true><<<dim3(BATCH * (NPIX / 16)), dim3(256), 0, stream>>>(
        fT, gT, attn_out, ast);
    pv_kernel<true><<<dim3(BATCH * (NPIX / 64)), dim3(256), 0, stream>>>(
        hh, ast, attn_out, x, gamma, outp);
  } else {
    attn_kernel<false><<<dim3(BATCH * (NPIX / 16)), dim3(256), 0, stream>>>(
        fT, gT, attn_out, ast);
    pv_kernel<false><<<dim3(BATCH * (NPIX / 64)), dim3(256), 0, stream>>>(
        hh, ast, attn_out, x, gamma, outp);
  }
}